// Round 7
// baseline (173.723 us; speedup 1.0000x reference)
//
#include <hip/hip_runtime.h>

// Problem constants (fixed by setup_inputs): B=4,T=32,H=224,W=224,C=3
namespace {
constexpr int B_ = 4, T_ = 32, H_ = 224, W_ = 224;
constexpr int HW_ = H_ * W_;              // 50176
constexpr int NPIX_ = B_ * T_ * HW_;      // 6422528
constexpr int N1_ = 79;                   // int(6422528*0.2*0.8 // 13005)
constexpr int N2_ = 9;                    // int(6422528*0.2*0.1 // 13005)
constexpr int NBOX_RW_ = N1_ + N2_;       // 88 boxes affect pixel output
constexpr int NBOX_M_  = N1_ + 2 * N2_;   // 97 boxes affect M
constexpr int HALF_T = 2, HALF_HW = 25;
constexpr int GPT_ = 16;                  // pixels per mask word
constexpr int GPR_ = W_ / GPT_;           // 14 words per row
constexpr int GPS_ = H_ * GPR_;           // 3136 words per slice
constexpr int NGRP_ = B_ * T_ * GPS_;     // 401408 words total
}

typedef float floatx4 __attribute__((ext_vector_type(4)));

// One block per (b,t) slice. Stages applicable rects in LDS (order
// irrelevant: R2 always wins over R1, values within a class identical),
// then emits one u32 mask per 16-pixel group: m1 bits 0..15, m2 bits 16..31.
// Also writes per-slice M flags and gathers random_token.
__global__ __launch_bounds__(256) void build_masks(
    const float* __restrict__ frames,
    const int* __restrict__ bb, const int* __restrict__ tt,
    const int* __restrict__ hh, const int* __restrict__ ww,
    const int* __restrict__ rb, const int* __restrict__ rt,
    const int* __restrict__ rh, const int* __restrict__ rw,
    unsigned* __restrict__ gmask, float* __restrict__ rtok,
    float* __restrict__ Mout)
{
    __shared__ int4 r1[NBOX_RW_];
    __shared__ int4 r2[N2_];
    __shared__ int c1, c2, c3;
    const int s = blockIdx.x;
    const int tid = threadIdx.x;
    if (tid == 0) { c1 = 0; c2 = 0; c3 = 0; }
    __syncthreads();

    if (s == 0 && tid == 0) {
        long idx = (((long)rb[0] * T_ + rt[0]) * H_ + rh[0]) * W_ + rw[0];
        rtok[0] = frames[idx * 3 + 0];
        rtok[1] = frames[idx * 3 + 1];
        rtok[2] = frames[idx * 3 + 2];
    }

    const int sb = s / T_, st = s % T_;
    if (tid < NBOX_M_) {
        const int i = tid;
        int tlo = max(tt[i] - HALF_T, 0);
        int thi = min(tt[i] + HALF_T, T_ - 1);   // exclusive (ref uses size-1)
        if (bb[i] == sb && st >= tlo && st < thi) {
            if (i >= NBOX_RW_) {
                atomicAdd(&c3, 1);               // R3: M only
            } else {
                int4 r;
                r.x = max(hh[i] - HALF_HW, 0);
                r.y = min(hh[i] + HALF_HW, H_ - 1);   // exclusive
                r.z = max(ww[i] - HALF_HW, 0);
                r.w = min(ww[i] + HALF_HW, W_ - 1);   // exclusive
                if (i < N1_) r1[atomicAdd(&c1, 1)] = r;
                else         r2[atomicAdd(&c2, 1)] = r;
            }
        }
    }
    __syncthreads();

    if (tid == 0) Mout[s] = (c1 + c2 + c3) > 0 ? 1.0f : 0.0f;

    const int n1 = c1, n2 = c2;
    for (int g = tid; g < GPS_; g += 256) {
        int h  = g / GPR_;
        int w0 = (g - h * GPR_) * GPT_;
        unsigned m1 = 0, m2 = 0;
        for (int j = 0; j < n1; ++j) {
            int4 r = r1[j];
            if (h >= r.x && h < r.y) {
                int lo = max(r.z - w0, 0), hi = min(r.w - w0, GPT_);
                if (hi > lo) m1 |= ((1u << (hi - lo)) - 1u) << lo;
            }
        }
        for (int j = 0; j < n2; ++j) {
            int4 r = r2[j];
            if (h >= r.x && h < r.y) {
                int lo = max(r.z - w0, 0), hi = min(r.w - w0, GPT_);
                if (hi > lo) m2 |= ((1u << (hi - lo)) - 1u) << lo;
            }
        }
        gmask[s * GPS_ + g] = m1 | (m2 << 16);
    }
}

// Write-only token scatter: out already holds a verbatim copy of frames
// (driver D2D blit). Masked pixels take token values unconditionally, so no
// frame reads are needed. One thread per 16-px group (192 B). ~84% of threads
// exit after one L2-hot u32 load. Fully-masked uniform groups (box interiors)
// take the 12x float4 fast path; box edges fall back to per-pixel stores.
__global__ __launch_bounds__(256) void scatter_tokens(
    const unsigned* __restrict__ gmask, const float* __restrict__ mtok,
    const float* __restrict__ rtok, float* __restrict__ out)
{
    const int g = blockIdx.x * 256 + threadIdx.x;   // grid covers NGRP_ exactly
    const unsigned mw = gmask[g];
    if (!mw) return;
    const unsigned m1 = mw & 0xFFFFu, m2 = mw >> 16;
    float* base = out + (long)g * (GPT_ * 3);

    if ((m2 == 0u && m1 == 0xFFFFu) || m2 == 0xFFFFu) {
        const float* tk = (m2 == 0xFFFFu) ? rtok : mtok;
        float t0 = tk[0], t1 = tk[1], t2 = tk[2];
        floatx4 p0 = {t0, t1, t2, t0};
        floatx4 p1 = {t1, t2, t0, t1};
        floatx4 p2 = {t2, t0, t1, t2};
        floatx4* b4 = (floatx4*)base;               // g*192 B => 16B aligned
#pragma unroll
        for (int i = 0; i < 4; ++i) {
            b4[3 * i + 0] = p0;
            b4[3 * i + 1] = p1;
            b4[3 * i + 2] = p2;
        }
        return;
    }

    float a0 = mtok[0], a1 = mtok[1], a2 = mtok[2];
    float b0 = rtok[0], b1 = rtok[1], b2 = rtok[2];
#pragma unroll
    for (int k = 0; k < GPT_; ++k) {
        unsigned bit = 1u << k;
        if (m2 & bit) {
            base[3 * k + 0] = b0; base[3 * k + 1] = b1; base[3 * k + 2] = b2;
        } else if (m1 & bit) {
            base[3 * k + 0] = a0; base[3 * k + 1] = a1; base[3 * k + 2] = a2;
        }
    }
}

extern "C" void kernel_launch(void* const* d_in, const int* in_sizes, int n_in,
                              void* d_out, int out_size, void* d_ws, size_t ws_size,
                              hipStream_t stream)
{
    const float* frames = (const float*)d_in[0];
    const float* mtok   = (const float*)d_in[1];
    const int* b  = (const int*)d_in[2];
    const int* t  = (const int*)d_in[3];
    const int* h  = (const int*)d_in[4];
    const int* w  = (const int*)d_in[5];
    const int* rb = (const int*)d_in[6];
    const int* rt = (const int*)d_in[7];
    const int* rh = (const int*)d_in[8];
    const int* rw = (const int*)d_in[9];

    // ws layout: gmask u32[401408] (1.57 MB) | rtok f32[3]
    unsigned* gmask = (unsigned*)d_ws;
    float*    rtok  = (float*)((char*)d_ws + (size_t)NGRP_ * 4);

    float* out_frames = (float*)d_out;
    float* out_M      = out_frames + (long)NPIX_ * 3;   // (B,T) flags as floats

    // Bulk copy frames -> out via the driver's tuned D2D blit (graph memcpy
    // node). Disjoint from the M-flag region, so ordering vs build_masks is
    // only through the stream.
    hipMemcpyAsync(out_frames, frames, (size_t)NPIX_ * 3 * sizeof(float),
                   hipMemcpyDeviceToDevice, stream);

    build_masks<<<B_ * T_, 256, 0, stream>>>(frames, b, t, h, w, rb, rt, rh, rw,
                                             gmask, rtok, out_M);

    scatter_tokens<<<NGRP_ / 256, 256, 0, stream>>>(gmask, mtok, rtok,
                                                    out_frames);
}

// Round 8
// 162.954 us; speedup vs baseline: 1.0661x; 1.0661x over previous
//
#include <hip/hip_runtime.h>

// Problem constants (fixed by setup_inputs): B=4,T=32,H=224,W=224,C=3
namespace {
constexpr int B_ = 4, T_ = 32, H_ = 224, W_ = 224;
constexpr int HW_ = H_ * W_;              // 50176
constexpr int NPIX_ = B_ * T_ * HW_;      // 6422528
constexpr int N1_ = 79;                   // int(6422528*0.2*0.8 // 13005)
constexpr int N2_ = 9;                    // int(6422528*0.2*0.1 // 13005)
constexpr int NBOX_RW_ = N1_ + N2_;       // 88 boxes affect pixel output
constexpr int NBOX_M_  = N1_ + 2 * N2_;   // 97 boxes affect M
constexpr int HALF_T = 2, HALF_HW = 25;
constexpr int GPT_ = 16;                  // pixels per mask word
constexpr int GPR_ = W_ / GPT_;           // 14 words per row
constexpr int GPS_ = H_ * GPR_;           // 3136 words per slice
constexpr int NGRP_ = B_ * T_ * GPS_;     // 401408 words total
constexpr int F4_TOTAL_ = NPIX_ * 3 / 4;  // 4816896 float4s
constexpr int ABLK_ = F4_TOTAL_ / 256;    // 18816 blocks, 1 float4/thread
}

typedef float floatx4 __attribute__((ext_vector_type(4)));

// One block per (b,t) slice. Stages applicable rects in LDS (order
// irrelevant: R2 always wins over R1, values within a class identical),
// then emits one u32 mask per 16-pixel group: m1 bits 0..15, m2 bits 16..31.
// Also writes per-slice M flags and gathers random_token.
__global__ __launch_bounds__(256) void build_masks(
    const float* __restrict__ frames,
    const int* __restrict__ bb, const int* __restrict__ tt,
    const int* __restrict__ hh, const int* __restrict__ ww,
    const int* __restrict__ rb, const int* __restrict__ rt,
    const int* __restrict__ rh, const int* __restrict__ rw,
    unsigned* __restrict__ gmask, float* __restrict__ rtok,
    float* __restrict__ Mout)
{
    __shared__ int4 r1[NBOX_RW_];
    __shared__ int4 r2[N2_];
    __shared__ int c1, c2, c3;
    const int s = blockIdx.x;
    const int tid = threadIdx.x;
    if (tid == 0) { c1 = 0; c2 = 0; c3 = 0; }
    __syncthreads();

    if (s == 0 && tid == 0) {
        long idx = (((long)rb[0] * T_ + rt[0]) * H_ + rh[0]) * W_ + rw[0];
        rtok[0] = frames[idx * 3 + 0];
        rtok[1] = frames[idx * 3 + 1];
        rtok[2] = frames[idx * 3 + 2];
    }

    const int sb = s / T_, st = s % T_;
    if (tid < NBOX_M_) {
        const int i = tid;
        int tlo = max(tt[i] - HALF_T, 0);
        int thi = min(tt[i] + HALF_T, T_ - 1);   // exclusive (ref uses size-1)
        if (bb[i] == sb && st >= tlo && st < thi) {
            if (i >= NBOX_RW_) {
                atomicAdd(&c3, 1);               // R3: M only
            } else {
                int4 r;
                r.x = max(hh[i] - HALF_HW, 0);
                r.y = min(hh[i] + HALF_HW, H_ - 1);   // exclusive
                r.z = max(ww[i] - HALF_HW, 0);
                r.w = min(ww[i] + HALF_HW, W_ - 1);   // exclusive
                if (i < N1_) r1[atomicAdd(&c1, 1)] = r;
                else         r2[atomicAdd(&c2, 1)] = r;
            }
        }
    }
    __syncthreads();

    if (tid == 0) Mout[s] = (c1 + c2 + c3) > 0 ? 1.0f : 0.0f;

    const int n1 = c1, n2 = c2;
    for (int g = tid; g < GPS_; g += 256) {
        int h  = g / GPR_;
        int w0 = (g - h * GPR_) * GPT_;
        unsigned m1 = 0, m2 = 0;
        for (int j = 0; j < n1; ++j) {
            int4 r = r1[j];
            if (h >= r.x && h < r.y) {
                int lo = max(r.z - w0, 0), hi = min(r.w - w0, GPT_);
                if (hi > lo) m1 |= ((1u << (hi - lo)) - 1u) << lo;
            }
        }
        for (int j = 0; j < n2; ++j) {
            int4 r = r2[j];
            if (h >= r.x && h < r.y) {
                int lo = max(r.z - w0, 0), hi = min(r.w - w0, GPT_);
                if (hi > lo) m2 |= ((1u << (hi - lo)) - 1u) << lo;
            }
        }
        gmask[s * GPS_ + g] = m1 | (m2 << 16);
    }
}

// Hot kernel: structural clone of the 6.7 TB/s fill — ONE float4 per thread,
// massive grid (launch-streaming), nontemporal load AND store (no cache
// allocate in either direction; L3 is swept by the harness poison each
// iteration anyway). Mask lookup: 2 L2-hot u32 loads + ~10 int ops.
__global__ __launch_bounds__(256) void apply_mask(
    const floatx4* __restrict__ frames4, const float* __restrict__ mtok,
    const unsigned* __restrict__ gmask, const float* __restrict__ rtok,
    floatx4* __restrict__ out4)
{
    const unsigned g4 = blockIdx.x * 256u + threadIdx.x;
    // ph = (4*g4) % 3 = g4 % 3
    const unsigned q  = __umulhi(g4, 0xAAAAAAABu) >> 1;   // g4 / 3
    const unsigned ph = g4 - 3u * q;
    const unsigned m  = (4u * g4 - ph) * 0xAAAAAAABu;     // pixel of float j=0 (exact /3)
    const unsigned w0i = m >> 4;
    const unsigned wa = gmask[w0i];
    const unsigned wb = gmask[(m + 1u) >> 4];             // last pixel is m+1 at most

    floatx4 v = __builtin_nontemporal_load(&frames4[g4]);

    if (wa | wb) {
        float m0 = mtok[0], m1 = mtok[1], m2 = mtok[2];
        float r0 = rtok[0], r1 = rtok[1], r2 = rtok[2];
        // rotated tokens: slot j holds component (ph+j)%3 (slot 3 == slot 0)
        float a0 = ph == 0 ? m0 : (ph == 1 ? m1 : m2);
        float a1 = ph == 0 ? m1 : (ph == 1 ? m2 : m0);
        float a2 = ph == 0 ? m2 : (ph == 1 ? m0 : m1);
        float b0 = ph == 0 ? r0 : (ph == 1 ? r1 : r2);
        float b1 = ph == 0 ? r1 : (ph == 1 ? r2 : r0);
        float b2 = ph == 0 ? r2 : (ph == 1 ? r0 : r1);
        const unsigned d1 = (ph + 1) / 3, d2 = (ph + 2) / 3;
        unsigned p1 = m + d1, p2 = m + d2, p3 = m + 1u;
        unsigned w1 = ((p1 >> 4) == w0i) ? wa : wb;
        unsigned w2 = ((p2 >> 4) == w0i) ? wa : wb;
        unsigned w3 = ((p3 >> 4) == w0i) ? wa : wb;
        unsigned q0 = m & 15u, q1 = p1 & 15u, q2 = p2 & 15u, q3 = p3 & 15u;
        v.x = ((wa >> (q0 + 16)) & 1u) ? b0 : (((wa >> q0) & 1u) ? a0 : v.x);
        v.y = ((w1 >> (q1 + 16)) & 1u) ? b1 : (((w1 >> q1) & 1u) ? a1 : v.y);
        v.z = ((w2 >> (q2 + 16)) & 1u) ? b2 : (((w2 >> q2) & 1u) ? a2 : v.z);
        v.w = ((w3 >> (q3 + 16)) & 1u) ? b0 : (((w3 >> q3) & 1u) ? a0 : v.w);
    }

    __builtin_nontemporal_store(v, &out4[g4]);
}

extern "C" void kernel_launch(void* const* d_in, const int* in_sizes, int n_in,
                              void* d_out, int out_size, void* d_ws, size_t ws_size,
                              hipStream_t stream)
{
    const float* frames = (const float*)d_in[0];
    const float* mtok   = (const float*)d_in[1];
    const int* b  = (const int*)d_in[2];
    const int* t  = (const int*)d_in[3];
    const int* h  = (const int*)d_in[4];
    const int* w  = (const int*)d_in[5];
    const int* rb = (const int*)d_in[6];
    const int* rt = (const int*)d_in[7];
    const int* rh = (const int*)d_in[8];
    const int* rw = (const int*)d_in[9];

    // ws layout: gmask u32[401408] (1.57 MB) | rtok f32[3]
    unsigned* gmask = (unsigned*)d_ws;
    float*    rtok  = (float*)((char*)d_ws + (size_t)NGRP_ * 4);

    float* out_frames = (float*)d_out;
    float* out_M      = out_frames + (long)NPIX_ * 3;   // (B,T) flags as floats

    build_masks<<<B_ * T_, 256, 0, stream>>>(frames, b, t, h, w, rb, rt, rh, rw,
                                             gmask, rtok, out_M);

    apply_mask<<<ABLK_, 256, 0, stream>>>((const floatx4*)frames, mtok, gmask,
                                          rtok, (floatx4*)out_frames);
}